// Round 1
// baseline (6051.474 us; speedup 1.0000x reference)
//
#include <hip/hip_runtime.h>

#define IN_DIM 256
#define HID    128
#define LAT    64

// ---------------------------------------------------------------- degree
__global__ void deg_count_kernel(const int* __restrict__ dst, float* __restrict__ dinv, int E) {
    int e = blockIdx.x * blockDim.x + threadIdx.x;
    if (e < E) atomicAdd(&dinv[dst[e]], 1.0f);
}

__global__ void finish_dinv_kernel(float* __restrict__ dinv, int N) {
    int i = blockIdx.x * blockDim.x + threadIdx.x;
    if (i < N) dinv[i] = rsqrtf(dinv[i] + 1.0f);   // +1 for self-loop; deg>=1 always
}

__global__ void compute_norm_kernel(const int* __restrict__ src, const int* __restrict__ dst,
                                    const float* __restrict__ dinv, float* __restrict__ norm,
                                    int E, int ET) {
    int e = blockIdx.x * blockDim.x + threadIdx.x;
    if (e >= ET) return;
    if (e < E) {
        norm[e] = dinv[src[e]] * dinv[dst[e]];
    } else {
        float d = dinv[e - E];
        norm[e] = d * d;
    }
}

// ---------------------------------------------------------------- GEMM1: O[N,128] = X[N,256] @ W[256,128]
__global__ __launch_bounds__(256) void gemm1_kernel(const float* __restrict__ X,
                                                    const float* __restrict__ W,
                                                    float* __restrict__ O, int N) {
    __shared__ float As[16][68];    // [k][m], padded row stride 68 floats (16B aligned, 2-way max)
    __shared__ float Bs[16][HID];   // [k][n]
    const int block_row = blockIdx.x * 64;
    const int tid = threadIdx.x;
    const int tx = tid & 31;        // col group: cols tx*4 .. tx*4+3
    const int ty = tid >> 5;        // row group: rows ty*8 .. ty*8+7
    float acc[8][4] = {};

    for (int k0 = 0; k0 < IN_DIM; k0 += 16) {
        // A tile: 64 rows x 16 k ; each thread one float4 along k, store transposed
        {
            int r  = tid >> 2;          // 0..63
            int kk = (tid & 3) * 4;     // 0,4,8,12
            float4 v = make_float4(0.f, 0.f, 0.f, 0.f);
            if (block_row + r < N)
                v = *(const float4*)(X + (size_t)(block_row + r) * IN_DIM + k0 + kk);
            As[kk + 0][r] = v.x; As[kk + 1][r] = v.y; As[kk + 2][r] = v.z; As[kk + 3][r] = v.w;
        }
        // B tile: 16 x 128 floats = 512 float4, 2 per thread
        #pragma unroll
        for (int t = 0; t < 2; ++t) {
            int f4 = tid + t * 256;
            int kr = f4 >> 5;
            int cc = (f4 & 31) * 4;
            *(float4*)&Bs[kr][cc] = *(const float4*)(W + (size_t)(k0 + kr) * HID + cc);
        }
        __syncthreads();
        #pragma unroll
        for (int kk = 0; kk < 16; ++kk) {
            float4 a0 = *(const float4*)&As[kk][ty * 8];
            float4 a1 = *(const float4*)&As[kk][ty * 8 + 4];
            float4 b  = *(const float4*)&Bs[kk][tx * 4];
            float a[8] = {a0.x, a0.y, a0.z, a0.w, a1.x, a1.y, a1.z, a1.w};
            float bb[4] = {b.x, b.y, b.z, b.w};
            #pragma unroll
            for (int i = 0; i < 8; ++i)
                #pragma unroll
                for (int j = 0; j < 4; ++j)
                    acc[i][j] += a[i] * bb[j];
        }
        __syncthreads();
    }
    #pragma unroll
    for (int i = 0; i < 8; ++i) {
        int r = block_row + ty * 8 + i;
        if (r < N)
            *(float4*)(O + (size_t)r * HID + tx * 4) =
                make_float4(acc[i][0], acc[i][1], acc[i][2], acc[i][3]);
    }
}

// ---------------------------------------------------------------- scatter: out[dst] += in[src] * norm
__global__ void scatter_kernel(const float* __restrict__ in, float* __restrict__ out,
                               const int* __restrict__ src, const int* __restrict__ dst,
                               const float* __restrict__ norm, int E, int ET) {
    int idx = blockIdx.x * blockDim.x + threadIdx.x;     // (edge, chunk) pairs
    int total = ET * 32;                                  // 32 float4 chunks per edge
    if (idx >= total) return;
    int e = idx >> 5;
    int c = (idx & 31) * 4;
    int s, d;
    if (e < E) { s = src[e]; d = dst[e]; } else { s = d = e - E; }
    float n = norm[e];
    float4 v = *(const float4*)(in + (size_t)s * HID + c);
    float* o = out + (size_t)d * HID + c;
    atomicAdd(o + 0, v.x * n);
    atomicAdd(o + 1, v.y * n);
    atomicAdd(o + 2, v.z * n);
    atomicAdd(o + 3, v.w * n);
}

// ---------------------------------------------------------------- h = relu(agg + b1), in place
__global__ void bias_relu_kernel(float* __restrict__ agg, const float* __restrict__ b1, int N) {
    int idx = blockIdx.x * blockDim.x + threadIdx.x;     // float4 index
    int total = N * (HID / 4);
    if (idx >= total) return;
    int c = (idx & 31) * 4;
    float4 v = *(float4*)(agg + (size_t)idx * 4);
    float4 b = *(const float4*)(b1 + c);
    v.x = fmaxf(v.x + b.x, 0.f);
    v.y = fmaxf(v.y + b.y, 0.f);
    v.z = fmaxf(v.z + b.z, 0.f);
    v.w = fmaxf(v.w + b.w, 0.f);
    *(float4*)(agg + (size_t)idx * 4) = v;
}

// ---------------------------------------------------------------- GEMM2: mu/logstd = A[N,128] @ {Wmu,Wls}[128,64] + bias
__global__ __launch_bounds__(256) void gemm2_kernel(const float* __restrict__ A,
                                                    const float* __restrict__ Wmu,
                                                    const float* __restrict__ Wls,
                                                    const float* __restrict__ bmu,
                                                    const float* __restrict__ bls,
                                                    float* __restrict__ mu,
                                                    float* __restrict__ ls, int N) {
    __shared__ float As[16][68];
    __shared__ float Bs[16][HID];   // virtual 128 cols: 0..63 = Wmu, 64..127 = Wls
    const int block_row = blockIdx.x * 64;
    const int tid = threadIdx.x;
    const int tx = tid & 31;
    const int ty = tid >> 5;
    float acc[8][4] = {};

    for (int k0 = 0; k0 < HID; k0 += 16) {
        {
            int r  = tid >> 2;
            int kk = (tid & 3) * 4;
            float4 v = make_float4(0.f, 0.f, 0.f, 0.f);
            if (block_row + r < N)
                v = *(const float4*)(A + (size_t)(block_row + r) * HID + k0 + kk);
            As[kk + 0][r] = v.x; As[kk + 1][r] = v.y; As[kk + 2][r] = v.z; As[kk + 3][r] = v.w;
        }
        #pragma unroll
        for (int t = 0; t < 2; ++t) {
            int f4 = tid + t * 256;
            int kr = f4 >> 5;
            int cc = (f4 & 31) * 4;
            const float* Wsrc = (cc < 64) ? (Wmu + (size_t)(k0 + kr) * LAT + cc)
                                          : (Wls + (size_t)(k0 + kr) * LAT + (cc - 64));
            *(float4*)&Bs[kr][cc] = *(const float4*)Wsrc;
        }
        __syncthreads();
        #pragma unroll
        for (int kk = 0; kk < 16; ++kk) {
            float4 a0 = *(const float4*)&As[kk][ty * 8];
            float4 a1 = *(const float4*)&As[kk][ty * 8 + 4];
            float4 b  = *(const float4*)&Bs[kk][tx * 4];
            float a[8] = {a0.x, a0.y, a0.z, a0.w, a1.x, a1.y, a1.z, a1.w};
            float bb[4] = {b.x, b.y, b.z, b.w};
            #pragma unroll
            for (int i = 0; i < 8; ++i)
                #pragma unroll
                for (int j = 0; j < 4; ++j)
                    acc[i][j] += a[i] * bb[j];
        }
        __syncthreads();
    }
    const int col = tx * 4;
    float4 bias = (col < 64) ? *(const float4*)(bmu + col) : *(const float4*)(bls + (col - 64));
    #pragma unroll
    for (int i = 0; i < 8; ++i) {
        int r = block_row + ty * 8 + i;
        if (r < N) {
            float4 v = make_float4(acc[i][0] + bias.x, acc[i][1] + bias.y,
                                   acc[i][2] + bias.z, acc[i][3] + bias.w);
            if (col < 64) *(float4*)(mu + (size_t)r * LAT + col) = v;
            else          *(float4*)(ls + (size_t)r * LAT + (col - 64)) = v;
        }
    }
}

// ---------------------------------------------------------------- launch
extern "C" void kernel_launch(void* const* d_in, const int* in_sizes, int n_in,
                              void* d_out, int out_size, void* d_ws, size_t ws_size,
                              hipStream_t stream) {
    const float* x    = (const float*)d_in[0];
    const int*   edge = (const int*)d_in[1];
    const float* W1   = (const float*)d_in[2];
    const float* b1   = (const float*)d_in[3];
    const float* Wmu  = (const float*)d_in[4];
    const float* bmu  = (const float*)d_in[5];
    const float* Wls  = (const float*)d_in[6];
    const float* bls  = (const float*)d_in[7];

    const int N  = in_sizes[0] / IN_DIM;
    const int E  = in_sizes[1] / 2;
    const int ET = E + N;                    // edges + self-loops

    const int* src = edge;
    const int* dst = edge + E;

    // workspace layout (floats)
    float* t1   = (float*)d_ws;              // [N,128]; later reused as agg2
    float* agg  = t1 + (size_t)N * HID;      // [N,128]; later h in-place
    float* dinv = agg + (size_t)N * HID;     // [N]
    float* norm = dinv + N;                  // [ET]

    float* mu = (float*)d_out;               // [N,64]
    float* ls = mu + (size_t)N * LAT;        // [N,64]

    hipMemsetAsync(dinv, 0, (size_t)N * sizeof(float), stream);
    hipMemsetAsync(agg, 0, (size_t)N * HID * sizeof(float), stream);

    deg_count_kernel<<<(E + 255) / 256, 256, 0, stream>>>(dst, dinv, E);
    finish_dinv_kernel<<<(N + 255) / 256, 256, 0, stream>>>(dinv, N);
    compute_norm_kernel<<<(ET + 255) / 256, 256, 0, stream>>>(src, dst, dinv, norm, E, ET);

    gemm1_kernel<<<(N + 63) / 64, 256, 0, stream>>>(x, W1, t1, N);

    {   // scatter t1 -> agg
        long long total = (long long)ET * 32;
        int grid = (int)((total + 255) / 256);
        scatter_kernel<<<grid, 256, 0, stream>>>(t1, agg, src, dst, norm, E, ET);
    }

    bias_relu_kernel<<<(N * (HID / 4) + 255) / 256, 256, 0, stream>>>(agg, b1, N);

    hipMemsetAsync(t1, 0, (size_t)N * HID * sizeof(float), stream);

    {   // scatter h(=agg) -> agg2(=t1)
        long long total = (long long)ET * 32;
        int grid = (int)((total + 255) / 256);
        scatter_kernel<<<grid, 256, 0, stream>>>(agg, t1, src, dst, norm, E, ET);
    }

    gemm2_kernel<<<(N + 63) / 64, 256, 0, stream>>>(t1, Wmu, Wls, bmu, bls, mu, ls, N);
}

// Round 2
// 725.412 us; speedup vs baseline: 8.3421x; 8.3421x over previous
//
#include <hip/hip_runtime.h>

#define IN_DIM 256
#define HID    128
#define LAT    64

// ---------------------------------------------------------------- degree (int)
__global__ void deg_count_kernel(const int* __restrict__ dst, int* __restrict__ deg, int E) {
    int e = blockIdx.x * blockDim.x + threadIdx.x;
    if (e < E) atomicAdd(&deg[dst[e]], 1);
}

__global__ void dinv_kernel(const int* __restrict__ deg, float* __restrict__ dinv, int N) {
    int i = blockIdx.x * blockDim.x + threadIdx.x;
    if (i < N) dinv[i] = rsqrtf((float)deg[i] + 1.0f);   // +1 self-loop
}

// ---------------------------------------------------------------- scan: row_off = exclusive_scan(deg+1)
__global__ void scan_block_kernel(const int* __restrict__ deg, int* __restrict__ row_off,
                                  int* __restrict__ partials, int N) {
    __shared__ int s[256];
    int i = blockIdx.x * 256 + threadIdx.x;
    int v = (i < N) ? (deg[i] + 1) : 0;
    s[threadIdx.x] = v;
    __syncthreads();
    for (int off = 1; off < 256; off <<= 1) {
        int x = (threadIdx.x >= off) ? s[threadIdx.x - off] : 0;
        __syncthreads();
        s[threadIdx.x] += x;
        __syncthreads();
    }
    if (i < N) row_off[i + 1] = s[threadIdx.x];           // local inclusive
    if (threadIdx.x == 255) partials[blockIdx.x] = s[255];
}

__global__ void scan_partials_kernel(int* __restrict__ partials, int NB) {
    __shared__ int s[1024];
    int t = threadIdx.x;
    int v = (t < NB) ? partials[t] : 0;
    s[t] = v;
    __syncthreads();
    for (int off = 1; off < 1024; off <<= 1) {
        int x = (t >= off) ? s[t - off] : 0;
        __syncthreads();
        s[t] += x;
        __syncthreads();
    }
    if (t < NB) partials[t] = s[t] - v;                   // exclusive block offsets
}

__global__ void scan_finalize_kernel(const int* __restrict__ deg, int* __restrict__ row_off,
                                     int* __restrict__ cursor, const int* __restrict__ partials, int N) {
    int i = blockIdx.x * 256 + threadIdx.x;
    if (i >= N) return;
    int val = row_off[i + 1] + partials[blockIdx.x];
    row_off[i + 1] = val;
    cursor[i] = val - (deg[i] + 1);                       // exclusive = row start
    if (i == 0) row_off[0] = 0;
}

// ---------------------------------------------------------------- CSR fill
__global__ void fill_edges_kernel(const int* __restrict__ src, const int* __restrict__ dst,
                                  const float* __restrict__ dinv, int* __restrict__ cursor,
                                  int* __restrict__ csr_src, float* __restrict__ csr_norm, int E) {
    int e = blockIdx.x * blockDim.x + threadIdx.x;
    if (e >= E) return;
    int s = src[e], d = dst[e];
    int pos = atomicAdd(&cursor[d], 1);
    csr_src[pos]  = s;
    csr_norm[pos] = dinv[s] * dinv[d];
}

__global__ void fill_loops_kernel(const float* __restrict__ dinv, int* __restrict__ cursor,
                                  int* __restrict__ csr_src, float* __restrict__ csr_norm, int N) {
    int i = blockIdx.x * blockDim.x + threadIdx.x;
    if (i >= N) return;
    int pos = atomicAdd(&cursor[i], 1);
    csr_src[pos]  = i;
    float di = dinv[i];
    csr_norm[pos] = di * di;
}

// ---------------------------------------------------------------- aggregation: one wave per node (gather, no atomics)
__global__ __launch_bounds__(256) void agg_kernel(const float* __restrict__ in, float* __restrict__ out,
                                                  const int* __restrict__ row_off,
                                                  const int* __restrict__ csr_src,
                                                  const float* __restrict__ csr_norm,
                                                  const float* __restrict__ bias, int N, int do_relu) {
    int wid  = (blockIdx.x * 256 + threadIdx.x) >> 6;
    int lane = threadIdx.x & 63;
    if (wid >= N) return;
    int p = row_off[wid], end = row_off[wid + 1];
    const int col = lane * 2;
    float ax = 0.f, ay = 0.f;
    for (; p + 1 < end; p += 2) {                         // 2-edge unroll for MLP
        int   s0 = csr_src[p],     s1 = csr_src[p + 1];
        float n0 = csr_norm[p],    n1 = csr_norm[p + 1];
        float2 v0 = *(const float2*)(in + (size_t)s0 * HID + col);
        float2 v1 = *(const float2*)(in + (size_t)s1 * HID + col);
        ax += v0.x * n0; ay += v0.y * n0;
        ax += v1.x * n1; ay += v1.y * n1;
    }
    if (p < end) {
        int s0 = csr_src[p]; float n0 = csr_norm[p];
        float2 v0 = *(const float2*)(in + (size_t)s0 * HID + col);
        ax += v0.x * n0; ay += v0.y * n0;
    }
    if (bias) { ax += bias[col]; ay += bias[col + 1]; }
    if (do_relu) { ax = fmaxf(ax, 0.f); ay = fmaxf(ay, 0.f); }
    *(float2*)(out + (size_t)wid * HID + col) = make_float2(ax, ay);
}

// ---------------------------------------------------------------- GEMM1: O[N,128] = X[N,256] @ W[256,128]
__global__ __launch_bounds__(256) void gemm1_kernel(const float* __restrict__ X,
                                                    const float* __restrict__ W,
                                                    float* __restrict__ O, int N) {
    __shared__ float As[16][68];
    __shared__ float Bs[16][HID];
    const int block_row = blockIdx.x * 64;
    const int tid = threadIdx.x;
    const int tx = tid & 31;
    const int ty = tid >> 5;
    float acc[8][4] = {};

    for (int k0 = 0; k0 < IN_DIM; k0 += 16) {
        {
            int r  = tid >> 2;
            int kk = (tid & 3) * 4;
            float4 v = make_float4(0.f, 0.f, 0.f, 0.f);
            if (block_row + r < N)
                v = *(const float4*)(X + (size_t)(block_row + r) * IN_DIM + k0 + kk);
            As[kk + 0][r] = v.x; As[kk + 1][r] = v.y; As[kk + 2][r] = v.z; As[kk + 3][r] = v.w;
        }
        #pragma unroll
        for (int t = 0; t < 2; ++t) {
            int f4 = tid + t * 256;
            int kr = f4 >> 5;
            int cc = (f4 & 31) * 4;
            *(float4*)&Bs[kr][cc] = *(const float4*)(W + (size_t)(k0 + kr) * HID + cc);
        }
        __syncthreads();
        #pragma unroll
        for (int kk = 0; kk < 16; ++kk) {
            float4 a0 = *(const float4*)&As[kk][ty * 8];
            float4 a1 = *(const float4*)&As[kk][ty * 8 + 4];
            float4 b  = *(const float4*)&Bs[kk][tx * 4];
            float a[8] = {a0.x, a0.y, a0.z, a0.w, a1.x, a1.y, a1.z, a1.w};
            float bb[4] = {b.x, b.y, b.z, b.w};
            #pragma unroll
            for (int i = 0; i < 8; ++i)
                #pragma unroll
                for (int j = 0; j < 4; ++j)
                    acc[i][j] += a[i] * bb[j];
        }
        __syncthreads();
    }
    #pragma unroll
    for (int i = 0; i < 8; ++i) {
        int r = block_row + ty * 8 + i;
        if (r < N)
            *(float4*)(O + (size_t)r * HID + tx * 4) =
                make_float4(acc[i][0], acc[i][1], acc[i][2], acc[i][3]);
    }
}

// ---------------------------------------------------------------- GEMM2: mu/logstd = A[N,128] @ {Wmu,Wls} + bias
__global__ __launch_bounds__(256) void gemm2_kernel(const float* __restrict__ A,
                                                    const float* __restrict__ Wmu,
                                                    const float* __restrict__ Wls,
                                                    const float* __restrict__ bmu,
                                                    const float* __restrict__ bls,
                                                    float* __restrict__ mu,
                                                    float* __restrict__ ls, int N) {
    __shared__ float As[16][68];
    __shared__ float Bs[16][HID];   // cols 0..63 = Wmu, 64..127 = Wls
    const int block_row = blockIdx.x * 64;
    const int tid = threadIdx.x;
    const int tx = tid & 31;
    const int ty = tid >> 5;
    float acc[8][4] = {};

    for (int k0 = 0; k0 < HID; k0 += 16) {
        {
            int r  = tid >> 2;
            int kk = (tid & 3) * 4;
            float4 v = make_float4(0.f, 0.f, 0.f, 0.f);
            if (block_row + r < N)
                v = *(const float4*)(A + (size_t)(block_row + r) * HID + k0 + kk);
            As[kk + 0][r] = v.x; As[kk + 1][r] = v.y; As[kk + 2][r] = v.z; As[kk + 3][r] = v.w;
        }
        #pragma unroll
        for (int t = 0; t < 2; ++t) {
            int f4 = tid + t * 256;
            int kr = f4 >> 5;
            int cc = (f4 & 31) * 4;
            const float* Wsrc = (cc < 64) ? (Wmu + (size_t)(k0 + kr) * LAT + cc)
                                          : (Wls + (size_t)(k0 + kr) * LAT + (cc - 64));
            *(float4*)&Bs[kr][cc] = *(const float4*)Wsrc;
        }
        __syncthreads();
        #pragma unroll
        for (int kk = 0; kk < 16; ++kk) {
            float4 a0 = *(const float4*)&As[kk][ty * 8];
            float4 a1 = *(const float4*)&As[kk][ty * 8 + 4];
            float4 b  = *(const float4*)&Bs[kk][tx * 4];
            float a[8] = {a0.x, a0.y, a0.z, a0.w, a1.x, a1.y, a1.z, a1.w};
            float bb[4] = {b.x, b.y, b.z, b.w};
            #pragma unroll
            for (int i = 0; i < 8; ++i)
                #pragma unroll
                for (int j = 0; j < 4; ++j)
                    acc[i][j] += a[i] * bb[j];
        }
        __syncthreads();
    }
    const int col = tx * 4;
    float4 bias = (col < 64) ? *(const float4*)(bmu + col) : *(const float4*)(bls + (col - 64));
    #pragma unroll
    for (int i = 0; i < 8; ++i) {
        int r = block_row + ty * 8 + i;
        if (r < N) {
            float4 v = make_float4(acc[i][0] + bias.x, acc[i][1] + bias.y,
                                   acc[i][2] + bias.z, acc[i][3] + bias.w);
            if (col < 64) *(float4*)(mu + (size_t)r * LAT + col) = v;
            else          *(float4*)(ls + (size_t)r * LAT + (col - 64)) = v;
        }
    }
}

// ---------------------------------------------------------------- launch
extern "C" void kernel_launch(void* const* d_in, const int* in_sizes, int n_in,
                              void* d_out, int out_size, void* d_ws, size_t ws_size,
                              hipStream_t stream) {
    const float* x    = (const float*)d_in[0];
    const int*   edge = (const int*)d_in[1];
    const float* W1   = (const float*)d_in[2];
    const float* b1   = (const float*)d_in[3];
    const float* Wmu  = (const float*)d_in[4];
    const float* bmu  = (const float*)d_in[5];
    const float* Wls  = (const float*)d_in[6];
    const float* bls  = (const float*)d_in[7];

    const int N  = in_sizes[0] / IN_DIM;
    const int E  = in_sizes[1] / 2;
    const int ET = E + N;

    const int* src = edge;
    const int* dst = edge + E;

    // workspace layout
    float* t1       = (float*)d_ws;                 // [N,128]  x@W1, later agg2
    float* h        = t1 + (size_t)N * HID;         // [N,128]  relu(agg1+b1)
    float* csr_norm = h + (size_t)N * HID;          // [ET]
    float* dinv     = csr_norm + ET;                // [N]
    int*   csr_src  = (int*)(dinv + N);             // [ET]
    int*   row_off  = csr_src + ET;                 // [N+1]
    int*   cursor   = row_off + (N + 1);            // [N]
    int*   deg      = cursor + N;                   // [N]
    int*   partials = deg + N;                      // [<=1024]

    float* mu = (float*)d_out;                      // [N,64]
    float* ls = mu + (size_t)N * LAT;               // [N,64]

    const int NB = (N + 255) / 256;                 // scan blocks (<=1024)

    hipMemsetAsync(deg, 0, (size_t)N * sizeof(int), stream);

    deg_count_kernel<<<(E + 255) / 256, 256, 0, stream>>>(dst, deg, E);
    dinv_kernel<<<NB, 256, 0, stream>>>(deg, dinv, N);

    scan_block_kernel<<<NB, 256, 0, stream>>>(deg, row_off, partials, N);
    scan_partials_kernel<<<1, 1024, 0, stream>>>(partials, NB);
    scan_finalize_kernel<<<NB, 256, 0, stream>>>(deg, row_off, cursor, partials, N);

    fill_edges_kernel<<<(E + 255) / 256, 256, 0, stream>>>(src, dst, dinv, cursor, csr_src, csr_norm, E);
    fill_loops_kernel<<<NB, 256, 0, stream>>>(dinv, cursor, csr_src, csr_norm, N);

    gemm1_kernel<<<(N + 63) / 64, 256, 0, stream>>>(x, W1, t1, N);

    {   // layer-1 aggregation + bias + relu: t1 -> h
        int blocks = (int)(((long long)N * 64 + 255) / 256);
        agg_kernel<<<blocks, 256, 0, stream>>>(t1, h, row_off, csr_src, csr_norm, b1, N, 1);
    }
    {   // layer-2 aggregation: h -> t1 (reused)
        int blocks = (int)(((long long)N * 64 + 255) / 256);
        agg_kernel<<<blocks, 256, 0, stream>>>(h, t1, row_off, csr_src, csr_norm, nullptr, N, 0);
    }

    gemm2_kernel<<<(N + 63) / 64, 256, 0, stream>>>(t1, Wmu, Wls, bmu, bls, mu, ls, N);
}

// Round 3
// 554.701 us; speedup vs baseline: 10.9094x; 1.3078x over previous
//
#include <hip/hip_runtime.h>

#define IN_DIM 256
#define HID    128
#define LAT    64

typedef __attribute__((ext_vector_type(8))) short short8;
typedef __attribute__((ext_vector_type(4))) float floatx4;

// bf16 helpers (bit-level, round-to-nearest-even)
static __device__ __forceinline__ ushort f2bf(float f) {
    union { float f; uint u; } v; v.f = f;
    uint u = v.u;
    uint r = (u + 0x7fffu + ((u >> 16) & 1u)) >> 16;
    return (ushort)r;
}
static __device__ __forceinline__ float bf_lo(uint v) { return __uint_as_float(v << 16); }
static __device__ __forceinline__ float bf_hi(uint v) { return __uint_as_float(v & 0xffff0000u); }

// ---------------------------------------------------------------- degree (int)
__global__ void deg_count_kernel(const int* __restrict__ dst, int* __restrict__ deg, int E) {
    int e = blockIdx.x * blockDim.x + threadIdx.x;
    if (e < E) atomicAdd(&deg[dst[e]], 1);
}

__global__ void dinv_kernel(const int* __restrict__ deg, float* __restrict__ dinv, int N) {
    int i = blockIdx.x * blockDim.x + threadIdx.x;
    if (i < N) dinv[i] = rsqrtf((float)deg[i] + 1.0f);   // +1 self-loop
}

// ---------------------------------------------------------------- scan: row_off = exclusive_scan(deg+1)
__global__ void scan_block_kernel(const int* __restrict__ deg, int* __restrict__ row_off,
                                  int* __restrict__ partials, int N) {
    __shared__ int s[256];
    int i = blockIdx.x * 256 + threadIdx.x;
    int v = (i < N) ? (deg[i] + 1) : 0;
    s[threadIdx.x] = v;
    __syncthreads();
    for (int off = 1; off < 256; off <<= 1) {
        int x = (threadIdx.x >= off) ? s[threadIdx.x - off] : 0;
        __syncthreads();
        s[threadIdx.x] += x;
        __syncthreads();
    }
    if (i < N) row_off[i + 1] = s[threadIdx.x];
    if (threadIdx.x == 255) partials[blockIdx.x] = s[255];
}

__global__ void scan_partials_kernel(int* __restrict__ partials, int NB) {
    __shared__ int s[1024];
    int t = threadIdx.x;
    int v = (t < NB) ? partials[t] : 0;
    s[t] = v;
    __syncthreads();
    for (int off = 1; off < 1024; off <<= 1) {
        int x = (t >= off) ? s[t - off] : 0;
        __syncthreads();
        s[t] += x;
        __syncthreads();
    }
    if (t < NB) partials[t] = s[t] - v;
}

__global__ void scan_finalize_kernel(const int* __restrict__ deg, int* __restrict__ row_off,
                                     int* __restrict__ cursor, const int* __restrict__ partials, int N) {
    int i = blockIdx.x * 256 + threadIdx.x;
    if (i >= N) return;
    int val = row_off[i + 1] + partials[blockIdx.x];
    row_off[i + 1] = val;
    cursor[i] = val - (deg[i] + 1);
    if (i == 0) row_off[0] = 0;
}

// ---------------------------------------------------------------- CSR fill (interleaved int2{src, norm-bits})
__global__ void fill_edges_kernel(const int* __restrict__ src, const int* __restrict__ dst,
                                  const float* __restrict__ dinv, int* __restrict__ cursor,
                                  int2* __restrict__ csr, int E) {
    int e = blockIdx.x * blockDim.x + threadIdx.x;
    if (e >= E) return;
    int s = src[e], d = dst[e];
    int pos = atomicAdd(&cursor[d], 1);
    csr[pos] = make_int2(s, __float_as_int(dinv[s] * dinv[d]));
}

__global__ void fill_loops_kernel(const float* __restrict__ dinv, int* __restrict__ cursor,
                                  int2* __restrict__ csr, int N) {
    int i = blockIdx.x * blockDim.x + threadIdx.x;
    if (i >= N) return;
    int pos = atomicAdd(&cursor[i], 1);
    float di = dinv[i];
    csr[pos] = make_int2(i, __float_as_int(di * di));
}

// ---------------------------------------------------------------- W1 -> bf16 transposed [128 n][256 k]
__global__ void w1t_kernel(const float* __restrict__ W1, ushort* __restrict__ W1T) {
    int idx = blockIdx.x * 256 + threadIdx.x;
    if (idx >= IN_DIM * HID) return;
    int k = idx >> 7, n = idx & 127;
    W1T[n * IN_DIM + k] = f2bf(W1[idx]);
}

// ---------------------------------------------------------------- GEMM1 (MFMA bf16): t1[N,128]bf16 = x[N,256] @ W1
__global__ __launch_bounds__(256) void gemm1_mfma(const float* __restrict__ X,
                                                  const ushort* __restrict__ W1T,
                                                  ushort* __restrict__ O, int N) {
    __shared__ ushort As[64 * 32];    // [m][k] bf16, 4 KB
    __shared__ ushort Bs[128 * 32];   // [n][k] bf16, 8 KB
    __shared__ ushort Cs[64 * 128];   // epilogue repack, 16 KB
    const int tid  = threadIdx.x;
    const int wave = tid >> 6, lane = tid & 63;
    const int q = lane >> 4, ln = lane & 15;
    const int row0 = blockIdx.x * 64;
    floatx4 acc[8] = {};

    for (int k0 = 0; k0 < IN_DIM; k0 += 32) {
        // stage A: 64 rows x 32 k fp32 -> bf16
        #pragma unroll
        for (int t = 0; t < 2; ++t) {
            int j = t * 256 + tid;               // float4 id, 512 total
            int r = j >> 3, kc = (j & 7) * 4;
            float4 v = make_float4(0.f, 0.f, 0.f, 0.f);
            if (row0 + r < N)
                v = *(const float4*)(X + (size_t)(row0 + r) * IN_DIM + k0 + kc);
            *(ushort4*)(As + r * 32 + kc) =
                make_ushort4(f2bf(v.x), f2bf(v.y), f2bf(v.z), f2bf(v.w));
        }
        // stage B: 128 n x 32 k bf16 straight copy (already transposed)
        #pragma unroll
        for (int t = 0; t < 2; ++t) {
            int c = t * 256 + tid;               // 8-bf16 chunk id, 512 total
            int n = c >> 2, kc = (c & 3) * 8;
            *(int4*)(Bs + n * 32 + kc) = *(const int4*)(W1T + (size_t)n * IN_DIM + k0 + kc);
        }
        __syncthreads();
        short8 a = *(const short8*)(As + (wave * 16 + ln) * 32 + q * 8);
        #pragma unroll
        for (int t = 0; t < 8; ++t) {
            short8 b = *(const short8*)(Bs + (t * 16 + ln) * 32 + q * 8);
            acc[t] = __builtin_amdgcn_mfma_f32_16x16x32_bf16(a, b, acc[t], 0, 0, 0);
        }
        __syncthreads();
    }
    // epilogue: frag -> Cs (bf16) -> coalesced global
    #pragma unroll
    for (int t = 0; t < 8; ++t)
        #pragma unroll
        for (int r = 0; r < 4; ++r)
            Cs[(wave * 16 + q * 4 + r) * 128 + t * 16 + ln] = f2bf(acc[t][r]);
    __syncthreads();
    #pragma unroll
    for (int t = 0; t < 4; ++t) {
        int j = t * 256 + tid;                   // int4(8 bf16) id, 1024 total
        int r = j >> 4, c8 = (j & 15) * 8;
        if (row0 + r < N)
            *(int4*)(O + (size_t)(row0 + r) * HID + c8) = *(const int4*)(Cs + r * 128 + c8);
    }
}

// ---------------------------------------------------------------- aggregation: bf16 gather, one wave/node
// mode 1: +bias, relu, bf16 out ; mode 0: fp32 out
__global__ __launch_bounds__(256) void agg_kernel(const ushort* __restrict__ in,
                                                  void* __restrict__ outp,
                                                  const int* __restrict__ row_off,
                                                  const int2* __restrict__ csr,
                                                  const float* __restrict__ bias,
                                                  int N, int mode) {
    int wid  = (blockIdx.x * 256 + threadIdx.x) >> 6;
    int lane = threadIdx.x & 63;
    if (wid >= N) return;
    int p = row_off[wid], end = row_off[wid + 1];
    const int boff = lane * 2;
    float ax = 0.f, ay = 0.f;
    for (; p + 3 < end; p += 4) {
        int2 e0 = csr[p], e1 = csr[p + 1], e2 = csr[p + 2], e3 = csr[p + 3];
        uint v0 = *(const uint*)(in + (size_t)e0.x * HID + boff);
        uint v1 = *(const uint*)(in + (size_t)e1.x * HID + boff);
        uint v2 = *(const uint*)(in + (size_t)e2.x * HID + boff);
        uint v3 = *(const uint*)(in + (size_t)e3.x * HID + boff);
        float n0 = __int_as_float(e0.y), n1 = __int_as_float(e1.y);
        float n2 = __int_as_float(e2.y), n3 = __int_as_float(e3.y);
        ax += bf_lo(v0) * n0 + bf_lo(v1) * n1 + bf_lo(v2) * n2 + bf_lo(v3) * n3;
        ay += bf_hi(v0) * n0 + bf_hi(v1) * n1 + bf_hi(v2) * n2 + bf_hi(v3) * n3;
    }
    for (; p < end; ++p) {
        int2 e0 = csr[p];
        uint v0 = *(const uint*)(in + (size_t)e0.x * HID + boff);
        float n0 = __int_as_float(e0.y);
        ax += bf_lo(v0) * n0;
        ay += bf_hi(v0) * n0;
    }
    if (mode) {
        ax = fmaxf(ax + bias[boff], 0.f);
        ay = fmaxf(ay + bias[boff + 1], 0.f);
        uint packed = (uint)f2bf(ax) | ((uint)f2bf(ay) << 16);
        *(uint*)((ushort*)outp + (size_t)wid * HID + boff) = packed;
    } else {
        *(float2*)((float*)outp + (size_t)wid * HID + boff) = make_float2(ax, ay);
    }
}

// ---------------------------------------------------------------- GEMM2 (fp32): mu/ls = g[N,128] @ {Wmu,Wls} + bias
__global__ __launch_bounds__(256) void gemm2_kernel(const float* __restrict__ A,
                                                    const float* __restrict__ Wmu,
                                                    const float* __restrict__ Wls,
                                                    const float* __restrict__ bmu,
                                                    const float* __restrict__ bls,
                                                    float* __restrict__ mu,
                                                    float* __restrict__ ls, int N) {
    __shared__ float As[16][68];
    __shared__ float Bs[16][HID];   // cols 0..63 = Wmu, 64..127 = Wls
    const int block_row = blockIdx.x * 64;
    const int tid = threadIdx.x;
    const int tx = tid & 31;
    const int ty = tid >> 5;
    float acc[8][4] = {};

    for (int k0 = 0; k0 < HID; k0 += 16) {
        {
            int r  = tid >> 2;
            int kk = (tid & 3) * 4;
            float4 v = make_float4(0.f, 0.f, 0.f, 0.f);
            if (block_row + r < N)
                v = *(const float4*)(A + (size_t)(block_row + r) * HID + k0 + kk);
            As[kk + 0][r] = v.x; As[kk + 1][r] = v.y; As[kk + 2][r] = v.z; As[kk + 3][r] = v.w;
        }
        #pragma unroll
        for (int t = 0; t < 2; ++t) {
            int f4 = tid + t * 256;
            int kr = f4 >> 5;
            int cc = (f4 & 31) * 4;
            const float* Wsrc = (cc < 64) ? (Wmu + (size_t)(k0 + kr) * LAT + cc)
                                          : (Wls + (size_t)(k0 + kr) * LAT + (cc - 64));
            *(float4*)&Bs[kr][cc] = *(const float4*)Wsrc;
        }
        __syncthreads();
        #pragma unroll
        for (int kk = 0; kk < 16; ++kk) {
            float4 a0 = *(const float4*)&As[kk][ty * 8];
            float4 a1 = *(const float4*)&As[kk][ty * 8 + 4];
            float4 b  = *(const float4*)&Bs[kk][tx * 4];
            float a[8] = {a0.x, a0.y, a0.z, a0.w, a1.x, a1.y, a1.z, a1.w};
            float bb[4] = {b.x, b.y, b.z, b.w};
            #pragma unroll
            for (int i = 0; i < 8; ++i)
                #pragma unroll
                for (int j = 0; j < 4; ++j)
                    acc[i][j] += a[i] * bb[j];
        }
        __syncthreads();
    }
    const int col = tx * 4;
    float4 bias = (col < 64) ? *(const float4*)(bmu + col) : *(const float4*)(bls + (col - 64));
    #pragma unroll
    for (int i = 0; i < 8; ++i) {
        int r = block_row + ty * 8 + i;
        if (r < N) {
            float4 v = make_float4(acc[i][0] + bias.x, acc[i][1] + bias.y,
                                   acc[i][2] + bias.z, acc[i][3] + bias.w);
            if (col < 64) *(float4*)(mu + (size_t)r * LAT + col) = v;
            else          *(float4*)(ls + (size_t)r * LAT + (col - 64)) = v;
        }
    }
}

// ---------------------------------------------------------------- launch
extern "C" void kernel_launch(void* const* d_in, const int* in_sizes, int n_in,
                              void* d_out, int out_size, void* d_ws, size_t ws_size,
                              hipStream_t stream) {
    const float* x    = (const float*)d_in[0];
    const int*   edge = (const int*)d_in[1];
    const float* W1   = (const float*)d_in[2];
    const float* b1   = (const float*)d_in[3];
    const float* Wmu  = (const float*)d_in[4];
    const float* bmu  = (const float*)d_in[5];
    const float* Wls  = (const float*)d_in[6];
    const float* bls  = (const float*)d_in[7];

    const int N  = in_sizes[0] / IN_DIM;
    const int E  = in_sizes[1] / 2;
    const int ET = E + N;

    const int* src = edge;
    const int* dst = edge + E;

    // workspace layout
    ushort* t1b  = (ushort*)d_ws;                       // [N,128] bf16
    ushort* hb   = t1b + (size_t)N * HID;               // [N,128] bf16
    float*  g    = (float*)(hb + (size_t)N * HID);      // [N,128] fp32
    int2*   csr  = (int2*)(g + (size_t)N * HID);        // [ET] {src, norm}
    float*  dinv = (float*)(csr + ET);                  // [N]
    int* row_off = (int*)(dinv + N);                    // [N+1]
    int* cursor  = row_off + (N + 1);                   // [N]
    int* deg     = cursor + N;                          // [N]
    int* partials= deg + N;                             // [<=1024]
    ushort* W1T  = (ushort*)(partials + 1024);          // [128,256] bf16

    float* mu = (float*)d_out;                          // [N,64]
    float* ls = mu + (size_t)N * LAT;                   // [N,64]

    const int NB = (N + 255) / 256;

    hipMemsetAsync(deg, 0, (size_t)N * sizeof(int), stream);

    deg_count_kernel<<<(E + 255) / 256, 256, 0, stream>>>(dst, deg, E);
    dinv_kernel<<<NB, 256, 0, stream>>>(deg, dinv, N);

    scan_block_kernel<<<NB, 256, 0, stream>>>(deg, row_off, partials, N);
    scan_partials_kernel<<<1, 1024, 0, stream>>>(partials, NB);
    scan_finalize_kernel<<<NB, 256, 0, stream>>>(deg, row_off, cursor, partials, N);

    fill_edges_kernel<<<(E + 255) / 256, 256, 0, stream>>>(src, dst, dinv, cursor, csr, E);
    fill_loops_kernel<<<NB, 256, 0, stream>>>(dinv, cursor, csr, N);

    w1t_kernel<<<(IN_DIM * HID + 255) / 256, 256, 0, stream>>>(W1, W1T);
    gemm1_mfma<<<(N + 63) / 64, 256, 0, stream>>>(x, W1T, t1b, N);

    {   // layer-1 aggregation + bias + relu: t1b -> hb (bf16)
        int blocks = (int)(((long long)N * 64 + 255) / 256);
        agg_kernel<<<blocks, 256, 0, stream>>>(t1b, hb, row_off, csr, b1, N, 1);
    }
    {   // layer-2 aggregation: hb -> g (fp32)
        int blocks = (int)(((long long)N * 64 + 255) / 256);
        agg_kernel<<<blocks, 256, 0, stream>>>(hb, g, row_off, csr, nullptr, N, 0);
    }

    gemm2_kernel<<<(N + 63) / 64, 256, 0, stream>>>(g, Wmu, Wls, bmu, bls, mu, ls, N);
}

// Round 4
// 521.536 us; speedup vs baseline: 11.6032x; 1.0636x over previous
//
#include <hip/hip_runtime.h>

#define IN_DIM 256
#define HID    128
#define LAT    64

typedef __attribute__((ext_vector_type(8))) short short8;
typedef __attribute__((ext_vector_type(4))) float floatx4;

// bf16 helpers (bit-level, round-to-nearest-even)
static __device__ __forceinline__ ushort f2bf(float f) {
    union { float f; uint u; } v; v.f = f;
    uint u = v.u;
    uint r = (u + 0x7fffu + ((u >> 16) & 1u)) >> 16;
    return (ushort)r;
}
static __device__ __forceinline__ float bf_lo(uint v) { return __uint_as_float(v << 16); }
static __device__ __forceinline__ float bf_hi(uint v) { return __uint_as_float(v & 0xffff0000u); }

// ---------------------------------------------------------------- degree (int)
__global__ void deg_count_kernel(const int* __restrict__ dst, int* __restrict__ deg, int E) {
    int e = blockIdx.x * blockDim.x + threadIdx.x;
    if (e < E) atomicAdd(&deg[dst[e]], 1);
}

// ---------------------------------------------------------------- scan block (+ dinv fused)
__global__ void scan_block_kernel(const int* __restrict__ deg, int* __restrict__ row_off,
                                  int* __restrict__ partials, float* __restrict__ dinv, int N) {
    __shared__ int s[256];
    int i = blockIdx.x * 256 + threadIdx.x;
    int v = (i < N) ? (deg[i] + 1) : 0;          // +1 self-loop
    if (i < N) dinv[i] = rsqrtf((float)v);
    s[threadIdx.x] = v;
    __syncthreads();
    for (int off = 1; off < 256; off <<= 1) {
        int x = (threadIdx.x >= off) ? s[threadIdx.x - off] : 0;
        __syncthreads();
        s[threadIdx.x] += x;
        __syncthreads();
    }
    if (i < N) row_off[i + 1] = s[threadIdx.x];
    if (threadIdx.x == 255) partials[blockIdx.x] = s[255];
}

__global__ void scan_partials_kernel(int* __restrict__ partials, int NB) {
    __shared__ int s[1024];
    int t = threadIdx.x;
    int v = (t < NB) ? partials[t] : 0;
    s[t] = v;
    __syncthreads();
    for (int off = 1; off < 1024; off <<= 1) {
        int x = (t >= off) ? s[t - off] : 0;
        __syncthreads();
        s[t] += x;
        __syncthreads();
    }
    if (t < NB) partials[t] = s[t] - v;
}

__global__ void scan_finalize_kernel(const int* __restrict__ deg, int* __restrict__ row_off,
                                     int* __restrict__ cursor, const int* __restrict__ partials, int N) {
    int i = blockIdx.x * 256 + threadIdx.x;
    if (i >= N) return;
    int val = row_off[i + 1] + partials[blockIdx.x];
    row_off[i + 1] = val;
    cursor[i] = val - (deg[i] + 1);
    if (i == 0) row_off[0] = 0;
}

// ---------------------------------------------------------------- CSR fill (edges + self-loops, one kernel)
__global__ void fill_kernel(const int* __restrict__ src, const int* __restrict__ dst,
                            const float* __restrict__ dinv, int* __restrict__ cursor,
                            int2* __restrict__ csr, int E, int ET) {
    int e = blockIdx.x * blockDim.x + threadIdx.x;
    if (e >= ET) return;
    int s, d; float nv;
    if (e < E) { s = src[e]; d = dst[e]; nv = dinv[s] * dinv[d]; }
    else       { s = d = e - E; float di = dinv[s]; nv = di * di; }
    int pos = atomicAdd(&cursor[d], 1);
    csr[pos] = make_int2(s, __float_as_int(nv));
}

// ---------------------------------------------------------------- weights -> bf16 transposed (one kernel)
// W1T [128 n][256 k]; W2T [128 n][128 k] (n 0..63 = Wmu, 64..127 = Wls)
__global__ void prep_weights(const float* __restrict__ W1, const float* __restrict__ Wmu,
                             const float* __restrict__ Wls,
                             ushort* __restrict__ W1T, ushort* __restrict__ W2T) {
    int idx = blockIdx.x * 256 + threadIdx.x;
    if (idx < IN_DIM * HID) {                       // W1: idx = k*128+n
        int n = idx & 127, k = idx >> 7;
        W1T[n * IN_DIM + k] = f2bf(W1[idx]);
    } else {
        int j = idx - IN_DIM * HID;
        if (j < HID * LAT) {                        // Wmu: j = k*64+n
            int n = j & 63, k = j >> 6;
            W2T[n * HID + k] = f2bf(Wmu[j]);
        } else {
            int jj = j - HID * LAT;
            int n = jj & 63, k = jj >> 6;
            W2T[(64 + n) * HID + k] = f2bf(Wls[jj]);
        }
    }
}

// ---------------------------------------------------------------- GEMM1 (MFMA bf16): t1[N,128]bf16 = x[N,256] @ W1
__global__ __launch_bounds__(256) void gemm1_mfma(const float* __restrict__ X,
                                                  const ushort* __restrict__ W1T,
                                                  ushort* __restrict__ O, int N) {
    __shared__ ushort As[64 * 32];
    __shared__ ushort Bs[128 * 32];
    __shared__ ushort Cs[64 * 128];
    const int tid  = threadIdx.x;
    const int wave = tid >> 6, lane = tid & 63;
    const int q = lane >> 4, ln = lane & 15;
    const int row0 = blockIdx.x * 64;
    floatx4 acc[8] = {};

    for (int k0 = 0; k0 < IN_DIM; k0 += 32) {
        #pragma unroll
        for (int t = 0; t < 2; ++t) {
            int j = t * 256 + tid;               // float4 id, 512 total
            int r = j >> 3, kc = (j & 7) * 4;
            float4 v = make_float4(0.f, 0.f, 0.f, 0.f);
            if (row0 + r < N)
                v = *(const float4*)(X + (size_t)(row0 + r) * IN_DIM + k0 + kc);
            *(ushort4*)(As + r * 32 + kc) =
                make_ushort4(f2bf(v.x), f2bf(v.y), f2bf(v.z), f2bf(v.w));
        }
        #pragma unroll
        for (int t = 0; t < 2; ++t) {
            int c = t * 256 + tid;               // 8-bf16 chunk id, 512 total
            int n = c >> 2, kc = (c & 3) * 8;
            *(int4*)(Bs + n * 32 + kc) = *(const int4*)(W1T + (size_t)n * IN_DIM + k0 + kc);
        }
        __syncthreads();
        short8 a = *(const short8*)(As + (wave * 16 + ln) * 32 + q * 8);
        #pragma unroll
        for (int t = 0; t < 8; ++t) {
            short8 b = *(const short8*)(Bs + (t * 16 + ln) * 32 + q * 8);
            acc[t] = __builtin_amdgcn_mfma_f32_16x16x32_bf16(a, b, acc[t], 0, 0, 0);
        }
        __syncthreads();
    }
    #pragma unroll
    for (int t = 0; t < 8; ++t)
        #pragma unroll
        for (int r = 0; r < 4; ++r)
            Cs[(wave * 16 + q * 4 + r) * 128 + t * 16 + ln] = f2bf(acc[t][r]);
    __syncthreads();
    #pragma unroll
    for (int t = 0; t < 4; ++t) {
        int j = t * 256 + tid;                   // int4(8 bf16) id, 1024 total
        int r = j >> 4, c8 = (j & 15) * 8;
        if (row0 + r < N)
            *(int4*)(O + (size_t)(row0 + r) * HID + c8) = *(const int4*)(Cs + r * 128 + c8);
    }
}

// ---------------------------------------------------------------- aggregation v2: half-wave edge pairing
// lanes 0-31 process edge p, lanes 32-63 edge p+1; lane covers 4 cols (8 B load)
// output always bf16; mode 1: +bias, relu
__global__ __launch_bounds__(256) void agg_kernel(const ushort* __restrict__ in,
                                                  ushort* __restrict__ out,
                                                  const int* __restrict__ row_off,
                                                  const int2* __restrict__ csr,
                                                  const float* __restrict__ bias,
                                                  int N, int mode) {
    int wid  = (blockIdx.x * 256 + threadIdx.x) >> 6;
    int lane = threadIdx.x & 63;
    if (wid >= N) return;
    int p = row_off[wid], end = row_off[wid + 1];
    const int half = lane >> 5;
    const int boff = (lane & 31) * 4;            // ushort col offset
    float a0 = 0.f, a1 = 0.f, a2 = 0.f, a3 = 0.f;
    for (; p + 3 < end; p += 4) {                // 2 pairs per iter
        int2 e0 = csr[p + half];
        int2 e1 = csr[p + 2 + half];
        uint2 v0 = *(const uint2*)(in + (size_t)e0.x * HID + boff);
        uint2 v1 = *(const uint2*)(in + (size_t)e1.x * HID + boff);
        float n0 = __int_as_float(e0.y), n1 = __int_as_float(e1.y);
        a0 += bf_lo(v0.x) * n0 + bf_lo(v1.x) * n1;
        a1 += bf_hi(v0.x) * n0 + bf_hi(v1.x) * n1;
        a2 += bf_lo(v0.y) * n0 + bf_lo(v1.y) * n1;
        a3 += bf_hi(v0.y) * n0 + bf_hi(v1.y) * n1;
    }
    if (p + 1 < end) {                           // one full pair
        int2 e0 = csr[p + half];
        uint2 v0 = *(const uint2*)(in + (size_t)e0.x * HID + boff);
        float n0 = __int_as_float(e0.y);
        a0 += bf_lo(v0.x) * n0; a1 += bf_hi(v0.x) * n0;
        a2 += bf_lo(v0.y) * n0; a3 += bf_hi(v0.y) * n0;
        p += 2;
    }
    if (p < end && half == 0) {                  // single tail edge
        int2 e0 = csr[p];
        uint2 v0 = *(const uint2*)(in + (size_t)e0.x * HID + boff);
        float n0 = __int_as_float(e0.y);
        a0 += bf_lo(v0.x) * n0; a1 += bf_hi(v0.x) * n0;
        a2 += bf_lo(v0.y) * n0; a3 += bf_hi(v0.y) * n0;
    }
    a0 += __shfl_xor(a0, 32); a1 += __shfl_xor(a1, 32);
    a2 += __shfl_xor(a2, 32); a3 += __shfl_xor(a3, 32);
    if (half == 0) {
        if (mode) {
            a0 = fmaxf(a0 + bias[boff], 0.f);
            a1 = fmaxf(a1 + bias[boff + 1], 0.f);
            a2 = fmaxf(a2 + bias[boff + 2], 0.f);
            a3 = fmaxf(a3 + bias[boff + 3], 0.f);
        }
        uint2 pk;
        pk.x = (uint)f2bf(a0) | ((uint)f2bf(a1) << 16);
        pk.y = (uint)f2bf(a2) | ((uint)f2bf(a3) << 16);
        *(uint2*)(out + (size_t)wid * HID + boff) = pk;
    }
}

// ---------------------------------------------------------------- GEMM2 (MFMA bf16): mu/ls[N,64] = g[N,128] @ W2T + bias
__global__ __launch_bounds__(256) void gemm2_mfma(const ushort* __restrict__ G,
                                                  const ushort* __restrict__ W2T,
                                                  const float* __restrict__ bmu,
                                                  const float* __restrict__ bls,
                                                  float* __restrict__ mu,
                                                  float* __restrict__ ls, int N) {
    __shared__ ushort As[64 * 32];
    __shared__ ushort Bs[128 * 32];
    __shared__ float  Cs[64 * 128];
    const int tid  = threadIdx.x;
    const int wave = tid >> 6, lane = tid & 63;
    const int q = lane >> 4, ln = lane & 15;
    const int row0 = blockIdx.x * 64;
    floatx4 acc[8] = {};

    for (int k0 = 0; k0 < HID; k0 += 32) {
        {   // A: 64 rows x 32 k bf16, 256 int4 chunks, 1/thread
            int r = tid >> 2, kc = (tid & 3) * 8;
            int4 v = make_int4(0, 0, 0, 0);
            if (row0 + r < N) v = *(const int4*)(G + (size_t)(row0 + r) * HID + k0 + kc);
            *(int4*)(As + r * 32 + kc) = v;
        }
        #pragma unroll
        for (int t = 0; t < 2; ++t) {            // B: 128 n x 32 k
            int c = t * 256 + tid;
            int n = c >> 2, kc = (c & 3) * 8;
            *(int4*)(Bs + n * 32 + kc) = *(const int4*)(W2T + (size_t)n * HID + k0 + kc);
        }
        __syncthreads();
        short8 a = *(const short8*)(As + (wave * 16 + ln) * 32 + q * 8);
        #pragma unroll
        for (int t = 0; t < 8; ++t) {
            short8 b = *(const short8*)(Bs + (t * 16 + ln) * 32 + q * 8);
            acc[t] = __builtin_amdgcn_mfma_f32_16x16x32_bf16(a, b, acc[t], 0, 0, 0);
        }
        __syncthreads();
    }
    #pragma unroll
    for (int t = 0; t < 8; ++t)
        #pragma unroll
        for (int r = 0; r < 4; ++r)
            Cs[(wave * 16 + q * 4 + r) * 128 + t * 16 + ln] = acc[t][r];
    __syncthreads();
    #pragma unroll
    for (int t = 0; t < 8; ++t) {
        int j = t * 256 + tid;                   // float4 id, 2048 total
        int r = j >> 5, c4 = (j & 31) * 4;
        if (row0 + r < N) {
            float4 v = *(const float4*)(Cs + r * 128 + c4);
            if (c4 < 64) {
                float4 b = *(const float4*)(bmu + c4);
                *(float4*)(mu + (size_t)(row0 + r) * LAT + c4) =
                    make_float4(v.x + b.x, v.y + b.y, v.z + b.z, v.w + b.w);
            } else {
                float4 b = *(const float4*)(bls + (c4 - 64));
                *(float4*)(ls + (size_t)(row0 + r) * LAT + (c4 - 64)) =
                    make_float4(v.x + b.x, v.y + b.y, v.z + b.z, v.w + b.w);
            }
        }
    }
}

// ---------------------------------------------------------------- launch
extern "C" void kernel_launch(void* const* d_in, const int* in_sizes, int n_in,
                              void* d_out, int out_size, void* d_ws, size_t ws_size,
                              hipStream_t stream) {
    const float* x    = (const float*)d_in[0];
    const int*   edge = (const int*)d_in[1];
    const float* W1   = (const float*)d_in[2];
    const float* b1   = (const float*)d_in[3];
    const float* Wmu  = (const float*)d_in[4];
    const float* bmu  = (const float*)d_in[5];
    const float* Wls  = (const float*)d_in[6];
    const float* bls  = (const float*)d_in[7];

    const int N  = in_sizes[0] / IN_DIM;
    const int E  = in_sizes[1] / 2;
    const int ET = E + N;

    const int* src = edge;
    const int* dst = edge + E;

    // workspace layout
    ushort* t1b  = (ushort*)d_ws;                       // [N,128] bf16
    ushort* hb   = t1b + (size_t)N * HID;               // [N,128] bf16
    ushort* gb   = hb + (size_t)N * HID;                // [N,128] bf16
    int2*   csr  = (int2*)(gb + (size_t)N * HID);       // [ET]
    float*  dinv = (float*)(csr + ET);                  // [N]
    int* row_off = (int*)(dinv + N);                    // [N+1]
    int* cursor  = row_off + (N + 1);                   // [N]
    int* deg     = cursor + N;                          // [N]
    int* partials= deg + N;                             // [<=1024]
    ushort* W1T  = (ushort*)(partials + 1024);          // [128,256] bf16
    ushort* W2T  = W1T + IN_DIM * HID;                  // [128,128] bf16

    float* mu = (float*)d_out;                          // [N,64]
    float* ls = mu + (size_t)N * LAT;                   // [N,64]

    const int NB = (N + 255) / 256;

    hipMemsetAsync(deg, 0, (size_t)N * sizeof(int), stream);

    deg_count_kernel<<<(E + 255) / 256, 256, 0, stream>>>(dst, deg, E);
    scan_block_kernel<<<NB, 256, 0, stream>>>(deg, row_off, partials, dinv, N);
    scan_partials_kernel<<<1, 1024, 0, stream>>>(partials, NB);
    scan_finalize_kernel<<<NB, 256, 0, stream>>>(deg, row_off, cursor, partials, N);
    fill_kernel<<<(ET + 255) / 256, 256, 0, stream>>>(src, dst, dinv, cursor, csr, E, ET);

    prep_weights<<<(IN_DIM * HID + 2 * HID * LAT) / 256, 256, 0, stream>>>(W1, Wmu, Wls, W1T, W2T);
    gemm1_mfma<<<(N + 63) / 64, 256, 0, stream>>>(x, W1T, t1b, N);

    {   // layer-1 aggregation + bias + relu: t1b -> hb
        int blocks = (int)(((long long)N * 64 + 255) / 256);
        agg_kernel<<<blocks, 256, 0, stream>>>(t1b, hb, row_off, csr, b1, N, 1);
    }
    {   // layer-2 aggregation: hb -> gb
        int blocks = (int)(((long long)N * 64 + 255) / 256);
        agg_kernel<<<blocks, 256, 0, stream>>>(hb, gb, row_off, csr, nullptr, N, 0);
    }

    gemm2_mfma<<<(N + 63) / 64, 256, 0, stream>>>(gb, W2T, bmu, bls, mu, ls, N);
}

// Round 5
// 516.720 us; speedup vs baseline: 11.7113x; 1.0093x over previous
//
#include <hip/hip_runtime.h>

#define IN_DIM 256
#define HID    128
#define LAT    64

typedef __attribute__((ext_vector_type(8))) short short8;
typedef __attribute__((ext_vector_type(4))) float floatx4;

// bf16 helpers (bit-level, round-to-nearest-even)
static __device__ __forceinline__ ushort f2bf(float f) {
    union { float f; uint u; } v; v.f = f;
    uint u = v.u;
    uint r = (u + 0x7fffu + ((u >> 16) & 1u)) >> 16;
    return (ushort)r;
}
static __device__ __forceinline__ float bf_lo(uint v) { return __uint_as_float(v << 16); }
static __device__ __forceinline__ float bf_hi(uint v) { return __uint_as_float(v & 0xffff0000u); }

// ---------------------------------------------------------------- degree (int)
__global__ void deg_count_kernel(const int* __restrict__ dst, int* __restrict__ deg, int E) {
    int e = blockIdx.x * blockDim.x + threadIdx.x;
    if (e < E) atomicAdd(&deg[dst[e]], 1);
}

// ---------------------------------------------------------------- scan block (+ dinv fused)
__global__ void scan_block_kernel(const int* __restrict__ deg, int* __restrict__ row_off,
                                  int* __restrict__ partials, float* __restrict__ dinv, int N) {
    __shared__ int s[256];
    int i = blockIdx.x * 256 + threadIdx.x;
    int v = (i < N) ? (deg[i] + 1) : 0;          // +1 self-loop
    if (i < N) dinv[i] = rsqrtf((float)v);
    s[threadIdx.x] = v;
    __syncthreads();
    for (int off = 1; off < 256; off <<= 1) {
        int x = (threadIdx.x >= off) ? s[threadIdx.x - off] : 0;
        __syncthreads();
        s[threadIdx.x] += x;
        __syncthreads();
    }
    if (i < N) row_off[i + 1] = s[threadIdx.x];
    if (threadIdx.x == 255) partials[blockIdx.x] = s[255];
}

__global__ void scan_partials_kernel(int* __restrict__ partials, int NB) {
    __shared__ int s[1024];
    int t = threadIdx.x;
    int v = (t < NB) ? partials[t] : 0;
    s[t] = v;
    __syncthreads();
    for (int off = 1; off < 1024; off <<= 1) {
        int x = (t >= off) ? s[t - off] : 0;
        __syncthreads();
        s[t] += x;
        __syncthreads();
    }
    if (t < NB) partials[t] = s[t] - v;
}

__global__ void scan_finalize_kernel(const int* __restrict__ deg, int* __restrict__ row_off,
                                     int* __restrict__ cursor, const int* __restrict__ partials, int N) {
    int i = blockIdx.x * 256 + threadIdx.x;
    if (i >= N) return;
    int val = row_off[i + 1] + partials[blockIdx.x];
    row_off[i + 1] = val;
    cursor[i] = val - (deg[i] + 1);
    if (i == 0) row_off[0] = 0;
}

// ---------------------------------------------------------------- CSR fill v2: dst-range partitioned
// blockIdx & 7 selects a node range (~N/8); each range's CSR region (~1.7 MB)
// stays resident in one XCD L2 (blockIdx%8 -> XCD round-robin heuristic),
// turning random partial-line writebacks into full-line single writebacks.
#define FILL_SLICE 2048
__global__ __launch_bounds__(256) void fill_kernel(const int* __restrict__ src, const int* __restrict__ dst,
                                                   const float* __restrict__ dinv, int* __restrict__ cursor,
                                                   int2* __restrict__ csr, int E, int ET, int range_size) {
    const int r    = blockIdx.x & 7;
    const int lo   = r * range_size;
    const int hi   = lo + range_size;
    const int base = (blockIdx.x >> 3) * FILL_SLICE;
    #pragma unroll
    for (int i = 0; i < FILL_SLICE; i += 256) {
        int e = base + i + threadIdx.x;
        if (e < ET) {
            int s = -1, d;
            if (e < E) { d = dst[e]; }
            else       { d = e - E; s = d; }
            if (d >= lo && d < hi) {
                if (s < 0) s = src[e];
                float nv = dinv[s] * dinv[d];
                int pos = atomicAdd(&cursor[d], 1);
                csr[pos] = make_int2(s, __float_as_int(nv));
            }
        }
    }
}

// ---------------------------------------------------------------- weights -> bf16 transposed
// W1T [128 n][256 k]; W2T [128 n][128 k] (n 0..63 = Wmu, 64..127 = Wls)
__global__ void prep_weights(const float* __restrict__ W1, const float* __restrict__ Wmu,
                             const float* __restrict__ Wls,
                             ushort* __restrict__ W1T, ushort* __restrict__ W2T) {
    int idx = blockIdx.x * 256 + threadIdx.x;
    if (idx < IN_DIM * HID) {                       // W1: idx = k*128+n
        int n = idx & 127, k = idx >> 7;
        W1T[n * IN_DIM + k] = f2bf(W1[idx]);
    } else {
        int j = idx - IN_DIM * HID;
        if (j < HID * LAT) {                        // Wmu: j = k*64+n
            int n = j & 63, k = j >> 6;
            W2T[n * HID + k] = f2bf(Wmu[j]);
        } else {
            int jj = j - HID * LAT;
            int n = jj & 63, k = jj >> 6;
            W2T[(64 + n) * HID + k] = f2bf(Wls[jj]);
        }
    }
}

// ---------------------------------------------------------------- GEMM1 (MFMA bf16): t1[N,128]bf16 = x[N,256] @ W1
__global__ __launch_bounds__(256) void gemm1_mfma(const float* __restrict__ X,
                                                  const ushort* __restrict__ W1T,
                                                  ushort* __restrict__ O, int N) {
    __shared__ ushort As[64 * 32];
    __shared__ ushort Bs[128 * 32];
    __shared__ ushort Cs[64 * 128];
    const int tid  = threadIdx.x;
    const int wave = tid >> 6, lane = tid & 63;
    const int q = lane >> 4, ln = lane & 15;
    const int row0 = blockIdx.x * 64;
    floatx4 acc[8] = {};

    for (int k0 = 0; k0 < IN_DIM; k0 += 32) {
        #pragma unroll
        for (int t = 0; t < 2; ++t) {
            int j = t * 256 + tid;               // float4 id, 512 total
            int r = j >> 3, kc = (j & 7) * 4;
            float4 v = make_float4(0.f, 0.f, 0.f, 0.f);
            if (row0 + r < N)
                v = *(const float4*)(X + (size_t)(row0 + r) * IN_DIM + k0 + kc);
            *(ushort4*)(As + r * 32 + kc) =
                make_ushort4(f2bf(v.x), f2bf(v.y), f2bf(v.z), f2bf(v.w));
        }
        #pragma unroll
        for (int t = 0; t < 2; ++t) {
            int c = t * 256 + tid;               // 8-bf16 chunk id, 512 total
            int n = c >> 2, kc = (c & 3) * 8;
            *(int4*)(Bs + n * 32 + kc) = *(const int4*)(W1T + (size_t)n * IN_DIM + k0 + kc);
        }
        __syncthreads();
        short8 a = *(const short8*)(As + (wave * 16 + ln) * 32 + q * 8);
        #pragma unroll
        for (int t = 0; t < 8; ++t) {
            short8 b = *(const short8*)(Bs + (t * 16 + ln) * 32 + q * 8);
            acc[t] = __builtin_amdgcn_mfma_f32_16x16x32_bf16(a, b, acc[t], 0, 0, 0);
        }
        __syncthreads();
    }
    #pragma unroll
    for (int t = 0; t < 8; ++t)
        #pragma unroll
        for (int r = 0; r < 4; ++r)
            Cs[(wave * 16 + q * 4 + r) * 128 + t * 16 + ln] = f2bf(acc[t][r]);
    __syncthreads();
    #pragma unroll
    for (int t = 0; t < 4; ++t) {
        int j = t * 256 + tid;                   // int4(8 bf16) id, 1024 total
        int r = j >> 4, c8 = (j & 15) * 8;
        if (row0 + r < N)
            *(int4*)(O + (size_t)(row0 + r) * HID + c8) = *(const int4*)(Cs + r * 128 + c8);
    }
}

// ---------------------------------------------------------------- aggregation v3: quarter-wave edge grouping
// quarter q (16 lanes) processes edge p+q; lane covers 8 cols via one 16 B load.
// two shfl_xor steps combine quarters; quarter 0 stores 16 B/lane.
__global__ __launch_bounds__(256) void agg_kernel(const ushort* __restrict__ in,
                                                  ushort* __restrict__ out,
                                                  const int* __restrict__ row_off,
                                                  const int2* __restrict__ csr,
                                                  const float* __restrict__ bias,
                                                  int N, int mode) {
    int wid  = (blockIdx.x * 256 + threadIdx.x) >> 6;
    int lane = threadIdx.x & 63;
    if (wid >= N) return;
    int p = row_off[wid], end = row_off[wid + 1];
    const int q    = lane >> 4;
    const int boff = (lane & 15) * 8;            // ushort col offset (16 B per lane)
    float a0=0.f,a1=0.f,a2=0.f,a3=0.f,a4=0.f,a5=0.f,a6=0.f,a7=0.f;
    for (; p + 3 < end; p += 4) {
        int2 e = csr[p + q];
        uint4 v = *(const uint4*)(in + (size_t)e.x * HID + boff);
        float n = __int_as_float(e.y);
        a0 += bf_lo(v.x) * n; a1 += bf_hi(v.x) * n;
        a2 += bf_lo(v.y) * n; a3 += bf_hi(v.y) * n;
        a4 += bf_lo(v.z) * n; a5 += bf_hi(v.z) * n;
        a6 += bf_lo(v.w) * n; a7 += bf_hi(v.w) * n;
    }
    int rem = end - p;                            // 0..3 tail edges
    if (q < rem) {
        int2 e = csr[p + q];
        uint4 v = *(const uint4*)(in + (size_t)e.x * HID + boff);
        float n = __int_as_float(e.y);
        a0 += bf_lo(v.x) * n; a1 += bf_hi(v.x) * n;
        a2 += bf_lo(v.y) * n; a3 += bf_hi(v.y) * n;
        a4 += bf_lo(v.z) * n; a5 += bf_hi(v.z) * n;
        a6 += bf_lo(v.w) * n; a7 += bf_hi(v.w) * n;
    }
    a0 += __shfl_xor(a0, 16); a1 += __shfl_xor(a1, 16);
    a2 += __shfl_xor(a2, 16); a3 += __shfl_xor(a3, 16);
    a4 += __shfl_xor(a4, 16); a5 += __shfl_xor(a5, 16);
    a6 += __shfl_xor(a6, 16); a7 += __shfl_xor(a7, 16);
    a0 += __shfl_xor(a0, 32); a1 += __shfl_xor(a1, 32);
    a2 += __shfl_xor(a2, 32); a3 += __shfl_xor(a3, 32);
    a4 += __shfl_xor(a4, 32); a5 += __shfl_xor(a5, 32);
    a6 += __shfl_xor(a6, 32); a7 += __shfl_xor(a7, 32);
    if (q == 0) {
        if (mode) {
            float4 b0 = *(const float4*)(bias + boff);
            float4 b1 = *(const float4*)(bias + boff + 4);
            a0 = fmaxf(a0 + b0.x, 0.f); a1 = fmaxf(a1 + b0.y, 0.f);
            a2 = fmaxf(a2 + b0.z, 0.f); a3 = fmaxf(a3 + b0.w, 0.f);
            a4 = fmaxf(a4 + b1.x, 0.f); a5 = fmaxf(a5 + b1.y, 0.f);
            a6 = fmaxf(a6 + b1.z, 0.f); a7 = fmaxf(a7 + b1.w, 0.f);
        }
        uint4 pk;
        pk.x = (uint)f2bf(a0) | ((uint)f2bf(a1) << 16);
        pk.y = (uint)f2bf(a2) | ((uint)f2bf(a3) << 16);
        pk.z = (uint)f2bf(a4) | ((uint)f2bf(a5) << 16);
        pk.w = (uint)f2bf(a6) | ((uint)f2bf(a7) << 16);
        *(uint4*)(out + (size_t)wid * HID + boff) = pk;
    }
}

// ---------------------------------------------------------------- GEMM2 (MFMA bf16): mu/ls[N,64] = g[N,128] @ W2T + bias
__global__ __launch_bounds__(256) void gemm2_mfma(const ushort* __restrict__ G,
                                                  const ushort* __restrict__ W2T,
                                                  const float* __restrict__ bmu,
                                                  const float* __restrict__ bls,
                                                  float* __restrict__ mu,
                                                  float* __restrict__ ls, int N) {
    __shared__ ushort As[64 * 32];
    __shared__ ushort Bs[128 * 32];
    __shared__ float  Cs[64 * 128];
    const int tid  = threadIdx.x;
    const int wave = tid >> 6, lane = tid & 63;
    const int q = lane >> 4, ln = lane & 15;
    const int row0 = blockIdx.x * 64;
    floatx4 acc[8] = {};

    for (int k0 = 0; k0 < HID; k0 += 32) {
        {   // A: 64 rows x 32 k bf16, 256 int4 chunks, 1/thread
            int r = tid >> 2, kc = (tid & 3) * 8;
            int4 v = make_int4(0, 0, 0, 0);
            if (row0 + r < N) v = *(const int4*)(G + (size_t)(row0 + r) * HID + k0 + kc);
            *(int4*)(As + r * 32 + kc) = v;
        }
        #pragma unroll
        for (int t = 0; t < 2; ++t) {            // B: 128 n x 32 k
            int c = t * 256 + tid;
            int n = c >> 2, kc = (c & 3) * 8;
            *(int4*)(Bs + n * 32 + kc) = *(const int4*)(W2T + (size_t)n * HID + k0 + kc);
        }
        __syncthreads();
        short8 a = *(const short8*)(As + (wave * 16 + ln) * 32 + q * 8);
        #pragma unroll
        for (int t = 0; t < 8; ++t) {
            short8 b = *(const short8*)(Bs + (t * 16 + ln) * 32 + q * 8);
            acc[t] = __builtin_amdgcn_mfma_f32_16x16x32_bf16(a, b, acc[t], 0, 0, 0);
        }
        __syncthreads();
    }
    #pragma unroll
    for (int t = 0; t < 8; ++t)
        #pragma unroll
        for (int r = 0; r < 4; ++r)
            Cs[(wave * 16 + q * 4 + r) * 128 + t * 16 + ln] = acc[t][r];
    __syncthreads();
    #pragma unroll
    for (int t = 0; t < 8; ++t) {
        int j = t * 256 + tid;                   // float4 id, 2048 total
        int r = j >> 5, c4 = (j & 31) * 4;
        if (row0 + r < N) {
            float4 v = *(const float4*)(Cs + r * 128 + c4);
            if (c4 < 64) {
                float4 b = *(const float4*)(bmu + c4);
                *(float4*)(mu + (size_t)(row0 + r) * LAT + c4) =
                    make_float4(v.x + b.x, v.y + b.y, v.z + b.z, v.w + b.w);
            } else {
                float4 b = *(const float4*)(bls + (c4 - 64));
                *(float4*)(ls + (size_t)(row0 + r) * LAT + (c4 - 64)) =
                    make_float4(v.x + b.x, v.y + b.y, v.z + b.z, v.w + b.w);
            }
        }
    }
}

// ---------------------------------------------------------------- launch
extern "C" void kernel_launch(void* const* d_in, const int* in_sizes, int n_in,
                              void* d_out, int out_size, void* d_ws, size_t ws_size,
                              hipStream_t stream) {
    const float* x    = (const float*)d_in[0];
    const int*   edge = (const int*)d_in[1];
    const float* W1   = (const float*)d_in[2];
    const float* b1   = (const float*)d_in[3];
    const float* Wmu  = (const float*)d_in[4];
    const float* bmu  = (const float*)d_in[5];
    const float* Wls  = (const float*)d_in[6];
    const float* bls  = (const float*)d_in[7];

    const int N  = in_sizes[0] / IN_DIM;
    const int E  = in_sizes[1] / 2;
    const int ET = E + N;

    const int* src = edge;
    const int* dst = edge + E;

    // workspace layout
    ushort* t1b  = (ushort*)d_ws;                       // [N,128] bf16
    ushort* hb   = t1b + (size_t)N * HID;               // [N,128] bf16
    ushort* gb   = hb + (size_t)N * HID;                // [N,128] bf16
    int2*   csr  = (int2*)(gb + (size_t)N * HID);       // [ET]
    float*  dinv = (float*)(csr + ET);                  // [N]
    int* row_off = (int*)(dinv + N);                    // [N+1]
    int* cursor  = row_off + (N + 1);                   // [N]
    int* deg     = cursor + N;                          // [N]
    int* partials= deg + N;                             // [<=1024]
    ushort* W1T  = (ushort*)(partials + 1024);          // [128,256] bf16
    ushort* W2T  = W1T + IN_DIM * HID;                  // [128,128] bf16

    float* mu = (float*)d_out;                          // [N,64]
    float* ls = mu + (size_t)N * LAT;                   // [N,64]

    const int NB = (N + 255) / 256;

    hipMemsetAsync(deg, 0, (size_t)N * sizeof(int), stream);

    deg_count_kernel<<<(E + 255) / 256, 256, 0, stream>>>(dst, deg, E);
    scan_block_kernel<<<NB, 256, 0, stream>>>(deg, row_off, partials, dinv, N);
    scan_partials_kernel<<<1, 1024, 0, stream>>>(partials, NB);
    scan_finalize_kernel<<<NB, 256, 0, stream>>>(deg, row_off, cursor, partials, N);

    {   // partitioned fill: (slices x 8 ranges) blocks
        int slices = (ET + FILL_SLICE - 1) / FILL_SLICE;
        int range_size = (N + 7) / 8;
        fill_kernel<<<slices * 8, 256, 0, stream>>>(src, dst, dinv, cursor, csr, E, ET, range_size);
    }

    prep_weights<<<(IN_DIM * HID + 2 * HID * LAT) / 256, 256, 0, stream>>>(W1, Wmu, Wls, W1T, W2T);
    gemm1_mfma<<<(N + 63) / 64, 256, 0, stream>>>(x, W1T, t1b, N);

    {   // layer-1 aggregation + bias + relu: t1b -> hb
        int blocks = (int)(((long long)N * 64 + 255) / 256);
        agg_kernel<<<blocks, 256, 0, stream>>>(t1b, hb, row_off, csr, b1, N, 1);
    }
    {   // layer-2 aggregation: hb -> gb
        int blocks = (int)(((long long)N * 64 + 255) / 256);
        agg_kernel<<<blocks, 256, 0, stream>>>(hb, gb, row_off, csr, nullptr, N, 0);
    }

    gemm2_mfma<<<(N + 63) / 64, 256, 0, stream>>>(gb, W2T, bmu, bls, mu, ls, N);
}